// Round 6
// baseline (171.873 us; speedup 1.0000x reference)
//
#include <hip/hip_runtime.h>
#include <hip/hip_bf16.h>

// GAT layer: B=8, N=8 (BN=64 batches), Nodes=512, IF=OF=256.
// MFMA on v_mfma_f32_16x16x32_bf16, split-bf16 (hi+lo) operands.
//
//  K0: detect dtype -> flag
//  KP: W -> Wt[f][k] bf16 hi/lo
//  KA: Wh = h@W. 512 blocks x 256 thr (2 blocks/CU). A reg-staged, B via
//      global_load_lds double-buffer, 2-phase barriers. (unchanged from r5)
//  KB: fused softmax (P pre-normalized bf16 in LDS) + out=elu(P@Wh).
//      512 blocks x 512 thr (8 waves). Wave w owns cols [w*32,w*32+32):
//      B staging is wave-private -> BARRIER-FREE K-loop, per-wave counted
//      vmcnt(4) 2-deep pipeline, setprio around MFMA. XCD-swizzled.

#define ALPHA 0.2f
#define MASK_VAL -9000000000000000.0f
#define NODES 512
#define FDIM 256
#define BN 64
#define SWZ(f) ((((f) ^ ((f) >> 2))) & 3)

typedef float  f32x4 __attribute__((ext_vector_type(4)));
typedef int    i32x4 __attribute__((ext_vector_type(4)));
typedef short  s16x8 __attribute__((ext_vector_type(8)));
typedef short  s16x4 __attribute__((ext_vector_type(4)));
typedef __bf16 bf16x8 __attribute__((ext_vector_type(8)));

__device__ __forceinline__ unsigned short f2bfu(float x) {
    __hip_bfloat16 b = __float2bfloat16(x);   // RNE
    unsigned short u; __builtin_memcpy(&u, &b, 2); return u;
}
__device__ __forceinline__ float bfu2f(unsigned short u) {
    unsigned int w = ((unsigned int)u) << 16; return __uint_as_float(w);
}
__device__ __forceinline__ f32x4 mfma16(s16x8 a, s16x8 b, f32x4 c) {
    return __builtin_amdgcn_mfma_f32_16x16x32_bf16(
        __builtin_bit_cast(bf16x8, a), __builtin_bit_cast(bf16x8, b), c, 0, 0, 0);
}

// hi/lo split of 8 fp32 (truncation split; residual ~2^-16 rel).
__device__ __forceinline__ void split8v(f32x4 v0, f32x4 v1, s16x8& hi, s16x8& lo)
{
    float x[8] = {v0[0], v0[1], v0[2], v0[3], v1[0], v1[1], v1[2], v1[3]};
    unsigned hw[4], lw[4];
    #pragma unroll
    for (int d = 0; d < 4; ++d) {
        const unsigned u0 = __float_as_uint(x[2*d]);
        const unsigned u1 = __float_as_uint(x[2*d + 1]);
        hw[d] = __builtin_amdgcn_perm(u1, u0, 0x07060302);
        const float l0 = x[2*d]     - __uint_as_float(u0 & 0xFFFF0000u);
        const float l1 = x[2*d + 1] - __uint_as_float(u1 & 0xFFFF0000u);
        lw[d] = __builtin_amdgcn_perm(__float_as_uint(l1), __float_as_uint(l0),
                                      0x07060302);
    }
    hi = __builtin_bit_cast(s16x8, *(unsigned(*)[4])hw);
    lo = __builtin_bit_cast(s16x8, *(unsigned(*)[4])lw);
}

__device__ __forceinline__ void gll16(const void* g, void* l) {
    __builtin_amdgcn_global_load_lds(
        (const __attribute__((address_space(1))) unsigned int*)g,
        (__attribute__((address_space(3))) unsigned int*)l,
        16, 0, 0);
}

// ---------------- K0: dtype detect ----------------
__global__ __launch_bounds__(256) void detect_kernel(const unsigned short* __restrict__ hraw,
                                                     int* __restrict__ flag)
{
    const int tid = threadIdx.x;
    float m = 0.0f;
    for (int i = tid; i < 16384; i += 256) {
        unsigned int w = ((unsigned int)hraw[i]) << 16;
        float v = __uint_as_float(w);
        v = fabsf(v);
        if (!(v == v)) v = 1e30f;
        m = fmaxf(m, v);
    }
    #pragma unroll
    for (int off = 32; off >= 1; off >>= 1)
        m = fmaxf(m, __shfl_down(m, off));
    __shared__ float red[4];
    if ((tid & 63) == 0) red[tid >> 6] = m;
    __syncthreads();
    if (tid == 0) {
        float mm = fmaxf(fmaxf(red[0], red[1]), fmaxf(red[2], red[3]));
        *flag = (mm > 1e4f) ? 1 : 0;
    }
}

// ---------------- KP: W -> Wt[f][k] bf16 hi/lo ----------------
__global__ __launch_bounds__(256) void prep_w_kernel(
    const void* __restrict__ Wv, const int* __restrict__ flagp,
    short* __restrict__ WtHi, short* __restrict__ WtLo)
{
    const int flag = *flagp;
    __shared__ float tile[16][17];
    const int tx = threadIdx.x & 15, ty = threadIdx.x >> 4;
    const int kk = blockIdx.y * 16 + ty;
    const int f  = blockIdx.x * 16 + tx;
    float v;
    if (flag) v = ((const float*)Wv)[kk * FDIM + f];
    else      v = bfu2f(((const unsigned short*)Wv)[kk * FDIM + f]);
    tile[ty][tx] = v;
    __syncthreads();
    const float x = tile[tx][ty];
    const int fo = blockIdx.x * 16 + ty;
    const int ko = blockIdx.y * 16 + tx;
    unsigned short h = f2bfu(x);
    WtHi[fo * FDIM + ko] = (short)h;
    WtLo[fo * FDIM + ko] = (short)f2bfu(x - bfu2f(h));  // exact 0 in bf16 mode
}

// ---------------- KA: Wh = h@W ----------------
// 512 blocks x 256 thr (4 waves, 2 blocks/CU). 64 rows x 256 cols, K=256.
// LDS: A [2 buf][hi 4K | lo 4K] at [0,16K); Bh [2][16K) at 16K; Bl at 48K.
__global__ __launch_bounds__(256, 2) void wh_gemm(
    const void* __restrict__ hv,
    const short* __restrict__ WtHi, const short* __restrict__ WtLo,
    const void* __restrict__ av, const int* __restrict__ flagp,
    short* __restrict__ WhTHi, short* __restrict__ WhTLo,
    float* __restrict__ srcv, float* __restrict__ dstv)
{
    __shared__ __align__(16) char smem[81920];

    const int flag = *flagp;
    const int blk = blockIdx.x;
    const int bn  = blk >> 3;
    const int i0  = (blk & 7) * 64;
    const size_t r0g = (size_t)blk * 64;
    const int tid = threadIdx.x;
    const int w = tid >> 6, l = tid & 63;
    const int fb = l & 15, g = l >> 4;

    // A staging map: thread -> (row, seg-slot).
    const int arow = tid >> 2, asg = tid & 3;
    const int aseg = asg ^ ((arow >> 1) & 3);
    const int awr  = arow * 64 + asg * 16;

    // B staging map: 4 (f, seg) pairs per thread, pointers precomputed.
    const short* gBh[4];
    const short* gBl[4];
    int bdst[4];
    {
        const int bsg = tid & 3;
        #pragma unroll
        for (int i = 0; i < 4; ++i) {
            const int f = i * 64 + (tid >> 2);
            const int ss = bsg ^ SWZ(f);
            gBh[i] = WtHi + f * FDIM + ss * 8;
            gBl[i] = WtLo + f * FDIM + ss * 8;
            bdst[i] = (i * 256 + tid) * 16;
        }
    }

    f32x4 acc[4][4];
    #pragma unroll
    for (int rt = 0; rt < 4; ++rt)
        #pragma unroll
        for (int ct = 0; ct < 4; ++ct) acc[rt][ct] = f32x4{0.f,0.f,0.f,0.f};

    if (flag) {
        const float* gA = (const float*)hv + (r0g + arow) * FDIM + aseg * 8;
        {
            f32x4 v0 = *(const f32x4*)gA;
            f32x4 v1 = *(const f32x4*)(gA + 4);
            #pragma unroll
            for (int i = 0; i < 4; ++i) {
                gll16(gBh[i], smem + 16384 + bdst[i]);
                gll16(gBl[i], smem + 49152 + bdst[i]);
            }
            s16x8 hi, lo; split8v(v0, v1, hi, lo);
            *(s16x8*)(smem + awr) = hi;
            *(s16x8*)(smem + 4096 + awr) = lo;
        }
        __syncthreads();
        for (int t = 0; t < 8; ++t) {
            const int cur = t & 1, nxt = cur ^ 1;
            f32x4 v0 = {}, v1 = {};
            if (t < 7) {
                v0 = *(const f32x4*)(gA + (t+1)*32);
                v1 = *(const f32x4*)(gA + (t+1)*32 + 4);
                #pragma unroll
                for (int i = 0; i < 4; ++i) {
                    gll16(gBh[i] + (t+1)*32, smem + 16384 + nxt*16384 + bdst[i]);
                    gll16(gBl[i] + (t+1)*32, smem + 49152 + nxt*16384 + bdst[i]);
                }
            }
            s16x8 bh[4], bl[4], ah[4], al[4];
            #pragma unroll
            for (int ct = 0; ct < 4; ++ct) {
                const int f = w*64 + ct*16 + fb;
                const int slot = g ^ SWZ(f);
                const int off = 16384 + cur*16384 + f*64 + slot*16;
                bh[ct] = *(const s16x8*)(smem + off);
                bl[ct] = *(const s16x8*)(smem + off + 32768);
            }
            #pragma unroll
            for (int rt = 0; rt < 4; ++rt) {
                const int row = rt*16 + fb;
                const int slot = g ^ ((row >> 1) & 3);
                const int off = cur*8192 + row*64 + slot*16;
                ah[rt] = *(const s16x8*)(smem + off);
                al[rt] = *(const s16x8*)(smem + off + 4096);
            }
            __builtin_amdgcn_s_setprio(1);
            #pragma unroll
            for (int rt = 0; rt < 4; ++rt)
                #pragma unroll
                for (int ct = 0; ct < 4; ++ct) {
                    acc[rt][ct] = mfma16(ah[rt], bh[ct], acc[rt][ct]);
                    acc[rt][ct] = mfma16(al[rt], bh[ct], acc[rt][ct]);
                    acc[rt][ct] = mfma16(ah[rt], bl[ct], acc[rt][ct]);
                }
            __builtin_amdgcn_s_setprio(0);
            if (t < 7) {
                s16x8 hi, lo; split8v(v0, v1, hi, lo);
                *(s16x8*)(smem + nxt*8192 + awr) = hi;
                *(s16x8*)(smem + nxt*8192 + 4096 + awr) = lo;
            }
            __syncthreads();
        }
    } else {
        const short* gA = (const short*)hv + (r0g + arow) * FDIM + aseg * 8;
        {
            s16x8 a0 = *(const s16x8*)gA;
            #pragma unroll
            for (int i = 0; i < 4; ++i) gll16(gBh[i], smem + 16384 + bdst[i]);
            *(s16x8*)(smem + awr) = a0;
        }
        __syncthreads();
        for (int t = 0; t < 8; ++t) {
            const int cur = t & 1, nxt = cur ^ 1;
            s16x8 an = {};
            if (t < 7) {
                an = *(const s16x8*)(gA + (t+1)*32);
                #pragma unroll
                for (int i = 0; i < 4; ++i)
                    gll16(gBh[i] + (t+1)*32, smem + 16384 + nxt*16384 + bdst[i]);
            }
            s16x8 bh[4], ah[4];
            #pragma unroll
            for (int ct = 0; ct < 4; ++ct) {
                const int f = w*64 + ct*16 + fb;
                const int slot = g ^ SWZ(f);
                bh[ct] = *(const s16x8*)(smem + 16384 + cur*16384 + f*64 + slot*16);
            }
            #pragma unroll
            for (int rt = 0; rt < 4; ++rt) {
                const int row = rt*16 + fb;
                const int slot = g ^ ((row >> 1) & 3);
                ah[rt] = *(const s16x8*)(smem + cur*8192 + row*64 + slot*16);
            }
            __builtin_amdgcn_s_setprio(1);
            #pragma unroll
            for (int rt = 0; rt < 4; ++rt)
                #pragma unroll
                for (int ct = 0; ct < 4; ++ct)
                    acc[rt][ct] = mfma16(ah[rt], bh[ct], acc[rt][ct]);
            __builtin_amdgcn_s_setprio(0);
            if (t < 7) *(s16x8*)(smem + nxt*8192 + awr) = an;
            __syncthreads();
        }
    }

    // Write WhT[bn][f][i] hi/lo. D: row = rt*16 + g*4 + r, col = f.
    const size_t wbT = (size_t)bn * FDIM * NODES;
    #pragma unroll
    for (int rt = 0; rt < 4; ++rt) {
        const int orow = i0 + rt * 16 + g * 4;
        #pragma unroll
        for (int ct = 0; ct < 4; ++ct) {
            const int f = w * 64 + ct * 16 + fb;
            s16x4 h4, l4;
            #pragma unroll
            for (int r = 0; r < 4; ++r) {
                float x = acc[rt][ct][r];
                unsigned short hh = f2bfu(x);
                h4[r] = (short)hh;
                l4[r] = (short)f2bfu(x - bfu2f(hh));
            }
            *(s16x4*)(WhTHi + wbT + (size_t)f * NODES + orow) = h4;
            *(s16x4*)(WhTLo + wbT + (size_t)f * NODES + orow) = l4;
        }
    }

    // src/dst reduction (fp32 accumulator path).
    float a1v[4], a2v[4];
    #pragma unroll
    for (int ct = 0; ct < 4; ++ct) {
        const int f = w * 64 + ct * 16 + fb;
        if (flag) {
            a1v[ct] = ((const float*)av)[f];
            a2v[ct] = ((const float*)av)[FDIM + f];
        } else {
            a1v[ct] = bfu2f(((const unsigned short*)av)[f]);
            a2v[ct] = bfu2f(((const unsigned short*)av)[FDIM + f]);
        }
    }
    float* red1 = (float*)smem;          // aliases dead A bufs
    float* red2 = red1 + 256;
    #pragma unroll
    for (int rt = 0; rt < 4; ++rt) {
        #pragma unroll
        for (int r = 0; r < 4; ++r) {
            float s1 = 0.f, s2 = 0.f;
            #pragma unroll
            for (int ct = 0; ct < 4; ++ct) {
                s1 = fmaf(acc[rt][ct][r], a1v[ct], s1);
                s2 = fmaf(acc[rt][ct][r], a2v[ct], s2);
            }
            #pragma unroll
            for (int off = 1; off <= 8; off <<= 1) {
                s1 += __shfl_xor(s1, off);
                s2 += __shfl_xor(s2, off);
            }
            if (fb == 0) {
                red1[w * 64 + rt * 16 + g * 4 + r] = s1;
                red2[w * 64 + rt * 16 + g * 4 + r] = s2;
            }
        }
    }
    __syncthreads();
    if (tid < 64) {
        srcv[bn * NODES + i0 + tid] =
            red1[tid] + red1[64 + tid] + red1[128 + tid] + red1[192 + tid];
        dstv[bn * NODES + i0 + tid] =
            red2[tid] + red2[64 + tid] + red2[128 + tid] + red2[192 + tid];
    }
}

// ---------------- KB: fused softmax + att@Wh + elu ----------------
// 512 blocks (XCD-swizzled) x 512 thr (8 waves). 64 rows, 256 cols, K=512.
// Wave w owns cols [w*32, w*32+32): B staging wave-private -> barrier-free
// K-loop with per-wave vmcnt(4) 2-deep pipeline. Ps 64K + 3 x 32K B bufs.
__global__ __launch_bounds__(512, 2) void pv_gemm(
    const short* __restrict__ WhTHi, const short* __restrict__ WhTLo,
    const float* __restrict__ srcv, const float* __restrict__ dstv,
    const int* __restrict__ adj, const int* __restrict__ flagp,
    void* __restrict__ out)
{
    __shared__ __align__(16) char smem[163840];   // Ps 64K | 3 x (hi16K+lo16K)

    const int flag = *flagp;
    const int b0 = blockIdx.x;
    const int blk = (b0 & 7) * 64 + (b0 >> 3);   // bijective: 512 % 8 == 0
    const int bn  = blk >> 3;
    const int i0  = (blk & 7) * 64;
    const int tid = threadIdx.x;
    const int w = tid >> 6, l = tid & 63;

    const short* bhig = WhTHi + (size_t)bn * FDIM * NODES;
    const short* blog = WhTLo + (size_t)bn * FDIM * NODES;

    // wave-private B staging: wave w stages its own f-slice [w*32, w*32+32).
    const int sf0 = w * 32 + (l >> 2);
    const int sf1 = sf0 + 16;
    const int sl  = l & 3;
    const short* gH0 = bhig + (size_t)sf0 * NODES + (sl ^ SWZ(sf0)) * 8;
    const short* gH1 = bhig + (size_t)sf1 * NODES + (sl ^ SWZ(sf1)) * 8;
    const short* gL0 = blog + (size_t)sf0 * NODES + (sl ^ SWZ(sf0)) * 8;
    const short* gL1 = blog + (size_t)sf1 * NODES + (sl ^ SWZ(sf1)) * 8;
    const int dB = (w * 32) * 64 + l * 16;   // hi dest (call 0) within buf

    auto stage = [&](int buf, int t) {
        const int ko = t * 32;
        char* base = smem + 65536 + buf * 32768;
        gll16(gH0 + ko, base + dB);
        gll16(gH1 + ko, base + dB + 1024);
        gll16(gL0 + ko, base + 16384 + dB);
        gll16(gL1 + ko, base + 16384 + dB + 1024);
    };

    stage(0, 0);
    stage(1, 1);   // tiles 0,1 land while softmax runs

    // ---- softmax: wave w -> rows w*8..w*8+8; lane l covers j = 8l..8l+8 ----
    {
        const float* drow = dstv + bn * NODES;
        const int j = l * 8;
        for (int rr = 0; rr < 8; ++rr) {
            const int r = w * 8 + rr;
            const int* adjrow = adj + (size_t)(i0 + r) * NODES;
            const float srow = srcv[bn * NODES + i0 + r];
            const i32x4 q0 = *(const i32x4*)(adjrow + j);
            const i32x4 q1 = *(const i32x4*)(adjrow + j + 4);
            const f32x4 d0 = *(const f32x4*)(drow + j);
            const f32x4 d1 = *(const f32x4*)(drow + j + 4);
            float e[8];
            #pragma unroll
            for (int k = 0; k < 4; ++k) {
                float ev = srow + d0[k];
                ev = (ev > 0.f) ? ev : ALPHA * ev;
                e[k] = (q0[k] > 0) ? ev : MASK_VAL;
                float ew = srow + d1[k];
                ew = (ew > 0.f) ? ew : ALPHA * ew;
                e[4 + k] = (q1[k] > 0) ? ew : MASK_VAL;
            }
            float m = e[0];
            #pragma unroll
            for (int k = 1; k < 8; ++k) m = fmaxf(m, e[k]);
            #pragma unroll
            for (int off = 1; off <= 32; off <<= 1) m = fmaxf(m, __shfl_xor(m, off));
            float p[8], s = 0.f;
            #pragma unroll
            for (int k = 0; k < 8; ++k) {
                p[k] = __expf(e[k] - m);   // masked -> 0; all-masked row -> 1
                s += p[k];
            }
            #pragma unroll
            for (int off = 1; off <= 32; off <<= 1) s += __shfl_xor(s, off);
            const float isum = 1.0f / s;
            s16x8 ph;
            #pragma unroll
            for (int k = 0; k < 8; ++k) ph[k] = (short)f2bfu(p[k] * isum);
            // chunk l stored at slot l ^ (r&7)
            *(s16x8*)(smem + r * 1024 + ((l ^ (r & 7)) * 16)) = ph;
        }
    }
    // Ps visible to all waves; keep prologue B loads in flight (lgkm-only drain)
    asm volatile("s_waitcnt lgkmcnt(0)" ::: "memory");
    __builtin_amdgcn_s_barrier();

    // ---- PV GEMM: 16 K-steps, barrier-free per-wave vmcnt pipeline ----
    const int fb = l & 15, g = l >> 4;

    unsigned boff[2];
    #pragma unroll
    for (int ct = 0; ct < 2; ++ct) {
        const int f = w * 32 + ct * 16 + fb;
        boff[ct] = (unsigned)(65536 + f * 64 + (g ^ SWZ(f)) * 16);
    }
    unsigned aoff[4];
    #pragma unroll
    for (int rt = 0; rt < 4; ++rt) {
        const int row = rt * 16 + fb;
        aoff[rt] = (unsigned)(row * 1024) | 0x80000000u * 0u;
    }

    f32x4 acc[4][2];
    #pragma unroll
    for (int rt = 0; rt < 4; ++rt)
        #pragma unroll
        for (int ct = 0; ct < 2; ++ct) acc[rt][ct] = f32x4{0.f,0.f,0.f,0.f};

    int cur = 0;
    for (int t = 0; t < 16; ++t) {
        if (t < 15) asm volatile("s_waitcnt vmcnt(4)" ::: "memory");
        else        asm volatile("s_waitcnt vmcnt(0)" ::: "memory");
        if (t < 14) {
            int nb = cur + 2; if (nb >= 3) nb -= 3;
            asm volatile("s_waitcnt lgkmcnt(0)" ::: "memory");
            stage(nb, t + 2);
        }
        const unsigned bbase = (unsigned)(cur * 32768);
        s16x8 bh[2], bl[2];
        #pragma unroll
        for (int ct = 0; ct < 2; ++ct) {
            bh[ct] = *(const s16x8*)(smem + bbase + boff[ct]);
            bl[ct] = *(const s16x8*)(smem + bbase + boff[ct] + 16384);
        }
        s16x8 af[4];
        #pragma unroll
        for (int rt = 0; rt < 4; ++rt) {
            const int row = rt * 16 + fb;
            const unsigned seg = (unsigned)(t * 4 + g) ^ (unsigned)(row & 7);
            af[rt] = *(const s16x8*)(smem + aoff[rt] + seg * 16);
        }
        __builtin_amdgcn_s_setprio(1);
        #pragma unroll
        for (int rt = 0; rt < 4; ++rt) {
            acc[rt][0] = mfma16(af[rt], bh[0], acc[rt][0]);
            acc[rt][0] = mfma16(af[rt], bl[0], acc[rt][0]);
            acc[rt][1] = mfma16(af[rt], bh[1], acc[rt][1]);
            acc[rt][1] = mfma16(af[rt], bl[1], acc[rt][1]);
        }
        __builtin_amdgcn_s_setprio(0);
        cur = cur + 1; if (cur == 3) cur = 0;
    }

    // epilogue: elu, store (P pre-normalized). D row = rt*16 + g*4 + r.
    #pragma unroll
    for (int rt = 0; rt < 4; ++rt) {
        #pragma unroll
        for (int ct = 0; ct < 2; ++ct) {
            const int f = w * 32 + ct * 16 + fb;
            #pragma unroll
            for (int r = 0; r < 4; ++r) {
                float v = acc[rt][ct][r];
                v = (v > 0.f) ? v : expm1f(v);
                const size_t o = ((size_t)bn * NODES + i0 + rt * 16 + g * 4 + r) * FDIM + f;
                if (flag) ((float*)out)[o] = v;
                else      ((unsigned short*)out)[o] = f2bfu(v);
            }
        }
    }
}

extern "C" void kernel_launch(void* const* d_in, const int* in_sizes, int n_in,
                              void* d_out, int out_size, void* d_ws, size_t ws_size,
                              hipStream_t stream)
{
    const void* h   = d_in[0];
    const int*  adj = (const int*)d_in[1];
    const void* W   = d_in[2];
    const void* a   = d_in[3];

    // ws layout: flag 256B | src 128K | dst 128K | WtHi 128K | WtLo 128K
    //            | WhTHi 16.78M | WhTLo 16.78M   (~34.1 MB total)
    int*   flag  = (int*)d_ws;
    float* srcv  = (float*)d_ws + 64;
    float* dstv  = srcv + BN * NODES;
    short* WtHi  = (short*)(dstv + BN * NODES);
    short* WtLo  = WtHi + FDIM * FDIM;
    short* WhTHi = WtLo + FDIM * FDIM;
    short* WhTLo = WhTHi + (size_t)BN * FDIM * NODES;

    detect_kernel<<<1, 256, 0, stream>>>((const unsigned short*)h, flag);
    prep_w_kernel<<<dim3(16, 16), 256, 0, stream>>>(W, flag, WtHi, WtLo);
    wh_gemm<<<512, 256, 0, stream>>>(h, WtHi, WtLo, a, flag,
                                     WhTHi, WhTLo, srcv, dstv);
    pv_gemm<<<512, 512, 0, stream>>>(WhTHi, WhTLo, srcv, dstv, adj, flag, d_out);
}

// Round 7
// 167.243 us; speedup vs baseline: 1.0277x; 1.0277x over previous
//
#include <hip/hip_runtime.h>
#include <hip/hip_bf16.h>

// GAT layer: B=8, N=8 (BN=64 batches), Nodes=512, IF=OF=256.
// MFMA on v_mfma_f32_16x16x32_bf16, split-bf16 (hi+lo) operands.
//
//  K0: detect dtype -> flag
//  KP: W -> Wt[f][k] bf16 hi/lo
//  KA: Wh = h@W. 512 blocks x 256 thr (2 blocks/CU). A reg-staged, B via
//      global_load_lds double-buffer, 2-phase barriers.
//  KB: fused softmax (P pre-normalized bf16 in LDS) + out=elu(P@Wh).
//      512 blocks x 512 thr (8 waves). Wave w owns cols [w*32,w*32+32):
//      B staging wave-private -> BARRIER-FREE K-loop with TRUE 2-tile
//      lookahead: stage(t+2) THEN s_waitcnt vmcnt(8)  (T4: N = 4 loads/tile
//      x 2 tiles in flight). setprio around MFMA. XCD-swizzled.

#define ALPHA 0.2f
#define MASK_VAL -9000000000000000.0f
#define NODES 512
#define FDIM 256
#define BN 64
#define SWZ(f) ((((f) ^ ((f) >> 2))) & 3)

typedef float  f32x4 __attribute__((ext_vector_type(4)));
typedef int    i32x4 __attribute__((ext_vector_type(4)));
typedef short  s16x8 __attribute__((ext_vector_type(8)));
typedef short  s16x4 __attribute__((ext_vector_type(4)));
typedef __bf16 bf16x8 __attribute__((ext_vector_type(8)));

__device__ __forceinline__ unsigned short f2bfu(float x) {
    __hip_bfloat16 b = __float2bfloat16(x);   // RNE
    unsigned short u; __builtin_memcpy(&u, &b, 2); return u;
}
__device__ __forceinline__ float bfu2f(unsigned short u) {
    unsigned int w = ((unsigned int)u) << 16; return __uint_as_float(w);
}
__device__ __forceinline__ f32x4 mfma16(s16x8 a, s16x8 b, f32x4 c) {
    return __builtin_amdgcn_mfma_f32_16x16x32_bf16(
        __builtin_bit_cast(bf16x8, a), __builtin_bit_cast(bf16x8, b), c, 0, 0, 0);
}

// hi/lo split of 8 fp32 (truncation split; residual ~2^-16 rel).
__device__ __forceinline__ void split8v(f32x4 v0, f32x4 v1, s16x8& hi, s16x8& lo)
{
    float x[8] = {v0[0], v0[1], v0[2], v0[3], v1[0], v1[1], v1[2], v1[3]};
    unsigned hw[4], lw[4];
    #pragma unroll
    for (int d = 0; d < 4; ++d) {
        const unsigned u0 = __float_as_uint(x[2*d]);
        const unsigned u1 = __float_as_uint(x[2*d + 1]);
        hw[d] = __builtin_amdgcn_perm(u1, u0, 0x07060302);
        const float l0 = x[2*d]     - __uint_as_float(u0 & 0xFFFF0000u);
        const float l1 = x[2*d + 1] - __uint_as_float(u1 & 0xFFFF0000u);
        lw[d] = __builtin_amdgcn_perm(__float_as_uint(l1), __float_as_uint(l0),
                                      0x07060302);
    }
    hi = __builtin_bit_cast(s16x8, *(unsigned(*)[4])hw);
    lo = __builtin_bit_cast(s16x8, *(unsigned(*)[4])lw);
}

__device__ __forceinline__ void gll16(const void* g, void* l) {
    __builtin_amdgcn_global_load_lds(
        (const __attribute__((address_space(1))) unsigned int*)g,
        (__attribute__((address_space(3))) unsigned int*)l,
        16, 0, 0);
}

// ---------------- K0: dtype detect ----------------
__global__ __launch_bounds__(256) void detect_kernel(const unsigned short* __restrict__ hraw,
                                                     int* __restrict__ flag)
{
    const int tid = threadIdx.x;
    float m = 0.0f;
    for (int i = tid; i < 16384; i += 256) {
        unsigned int w = ((unsigned int)hraw[i]) << 16;
        float v = __uint_as_float(w);
        v = fabsf(v);
        if (!(v == v)) v = 1e30f;
        m = fmaxf(m, v);
    }
    #pragma unroll
    for (int off = 32; off >= 1; off >>= 1)
        m = fmaxf(m, __shfl_down(m, off));
    __shared__ float red[4];
    if ((tid & 63) == 0) red[tid >> 6] = m;
    __syncthreads();
    if (tid == 0) {
        float mm = fmaxf(fmaxf(red[0], red[1]), fmaxf(red[2], red[3]));
        *flag = (mm > 1e4f) ? 1 : 0;
    }
}

// ---------------- KP: W -> Wt[f][k] bf16 hi/lo ----------------
__global__ __launch_bounds__(256) void prep_w_kernel(
    const void* __restrict__ Wv, const int* __restrict__ flagp,
    short* __restrict__ WtHi, short* __restrict__ WtLo)
{
    const int flag = *flagp;
    __shared__ float tile[16][17];
    const int tx = threadIdx.x & 15, ty = threadIdx.x >> 4;
    const int kk = blockIdx.y * 16 + ty;
    const int f  = blockIdx.x * 16 + tx;
    float v;
    if (flag) v = ((const float*)Wv)[kk * FDIM + f];
    else      v = bfu2f(((const unsigned short*)Wv)[kk * FDIM + f]);
    tile[ty][tx] = v;
    __syncthreads();
    const float x = tile[tx][ty];
    const int fo = blockIdx.x * 16 + ty;
    const int ko = blockIdx.y * 16 + tx;
    unsigned short h = f2bfu(x);
    WtHi[fo * FDIM + ko] = (short)h;
    WtLo[fo * FDIM + ko] = (short)f2bfu(x - bfu2f(h));  // exact 0 in bf16 mode
}

// ---------------- KA: Wh = h@W ----------------
// 512 blocks x 256 thr (4 waves, 2 blocks/CU). 64 rows x 256 cols, K=256.
// LDS: A [2 buf][hi 4K | lo 4K] at [0,16K); Bh [2][16K) at 16K; Bl at 48K.
__global__ __launch_bounds__(256, 2) void wh_gemm(
    const void* __restrict__ hv,
    const short* __restrict__ WtHi, const short* __restrict__ WtLo,
    const void* __restrict__ av, const int* __restrict__ flagp,
    short* __restrict__ WhTHi, short* __restrict__ WhTLo,
    float* __restrict__ srcv, float* __restrict__ dstv)
{
    __shared__ __align__(16) char smem[81920];

    const int flag = *flagp;
    const int blk = blockIdx.x;
    const int bn  = blk >> 3;
    const int i0  = (blk & 7) * 64;
    const size_t r0g = (size_t)blk * 64;
    const int tid = threadIdx.x;
    const int w = tid >> 6, l = tid & 63;
    const int fb = l & 15, g = l >> 4;

    // A staging map: thread -> (row, seg-slot).
    const int arow = tid >> 2, asg = tid & 3;
    const int aseg = asg ^ ((arow >> 1) & 3);
    const int awr  = arow * 64 + asg * 16;

    // B staging map: 4 (f, seg) pairs per thread, pointers precomputed.
    const short* gBh[4];
    const short* gBl[4];
    int bdst[4];
    {
        const int bsg = tid & 3;
        #pragma unroll
        for (int i = 0; i < 4; ++i) {
            const int f = i * 64 + (tid >> 2);
            const int ss = bsg ^ SWZ(f);
            gBh[i] = WtHi + f * FDIM + ss * 8;
            gBl[i] = WtLo + f * FDIM + ss * 8;
            bdst[i] = (i * 256 + tid) * 16;
        }
    }

    f32x4 acc[4][4];
    #pragma unroll
    for (int rt = 0; rt < 4; ++rt)
        #pragma unroll
        for (int ct = 0; ct < 4; ++ct) acc[rt][ct] = f32x4{0.f,0.f,0.f,0.f};

    if (flag) {
        const float* gA = (const float*)hv + (r0g + arow) * FDIM + aseg * 8;
        {
            f32x4 v0 = *(const f32x4*)gA;
            f32x4 v1 = *(const f32x4*)(gA + 4);
            #pragma unroll
            for (int i = 0; i < 4; ++i) {
                gll16(gBh[i], smem + 16384 + bdst[i]);
                gll16(gBl[i], smem + 49152 + bdst[i]);
            }
            s16x8 hi, lo; split8v(v0, v1, hi, lo);
            *(s16x8*)(smem + awr) = hi;
            *(s16x8*)(smem + 4096 + awr) = lo;
        }
        __syncthreads();
        for (int t = 0; t < 8; ++t) {
            const int cur = t & 1, nxt = cur ^ 1;
            f32x4 v0 = {}, v1 = {};
            if (t < 7) {
                v0 = *(const f32x4*)(gA + (t+1)*32);
                v1 = *(const f32x4*)(gA + (t+1)*32 + 4);
                #pragma unroll
                for (int i = 0; i < 4; ++i) {
                    gll16(gBh[i] + (t+1)*32, smem + 16384 + nxt*16384 + bdst[i]);
                    gll16(gBl[i] + (t+1)*32, smem + 49152 + nxt*16384 + bdst[i]);
                }
            }
            s16x8 bh[4], bl[4], ah[4], al[4];
            #pragma unroll
            for (int ct = 0; ct < 4; ++ct) {
                const int f = w*64 + ct*16 + fb;
                const int slot = g ^ SWZ(f);
                const int off = 16384 + cur*16384 + f*64 + slot*16;
                bh[ct] = *(const s16x8*)(smem + off);
                bl[ct] = *(const s16x8*)(smem + off + 32768);
            }
            #pragma unroll
            for (int rt = 0; rt < 4; ++rt) {
                const int row = rt*16 + fb;
                const int slot = g ^ ((row >> 1) & 3);
                const int off = cur*8192 + row*64 + slot*16;
                ah[rt] = *(const s16x8*)(smem + off);
                al[rt] = *(const s16x8*)(smem + off + 4096);
            }
            __builtin_amdgcn_s_setprio(1);
            #pragma unroll
            for (int rt = 0; rt < 4; ++rt)
                #pragma unroll
                for (int ct = 0; ct < 4; ++ct) {
                    acc[rt][ct] = mfma16(ah[rt], bh[ct], acc[rt][ct]);
                    acc[rt][ct] = mfma16(al[rt], bh[ct], acc[rt][ct]);
                    acc[rt][ct] = mfma16(ah[rt], bl[ct], acc[rt][ct]);
                }
            __builtin_amdgcn_s_setprio(0);
            if (t < 7) {
                s16x8 hi, lo; split8v(v0, v1, hi, lo);
                *(s16x8*)(smem + nxt*8192 + awr) = hi;
                *(s16x8*)(smem + nxt*8192 + 4096 + awr) = lo;
            }
            __syncthreads();
        }
    } else {
        const short* gA = (const short*)hv + (r0g + arow) * FDIM + aseg * 8;
        {
            s16x8 a0 = *(const s16x8*)gA;
            #pragma unroll
            for (int i = 0; i < 4; ++i) gll16(gBh[i], smem + 16384 + bdst[i]);
            *(s16x8*)(smem + awr) = a0;
        }
        __syncthreads();
        for (int t = 0; t < 8; ++t) {
            const int cur = t & 1, nxt = cur ^ 1;
            s16x8 an = {};
            if (t < 7) {
                an = *(const s16x8*)(gA + (t+1)*32);
                #pragma unroll
                for (int i = 0; i < 4; ++i)
                    gll16(gBh[i] + (t+1)*32, smem + 16384 + nxt*16384 + bdst[i]);
            }
            s16x8 bh[4], ah[4];
            #pragma unroll
            for (int ct = 0; ct < 4; ++ct) {
                const int f = w*64 + ct*16 + fb;
                const int slot = g ^ SWZ(f);
                bh[ct] = *(const s16x8*)(smem + 16384 + cur*16384 + f*64 + slot*16);
            }
            #pragma unroll
            for (int rt = 0; rt < 4; ++rt) {
                const int row = rt*16 + fb;
                const int slot = g ^ ((row >> 1) & 3);
                ah[rt] = *(const s16x8*)(smem + cur*8192 + row*64 + slot*16);
            }
            __builtin_amdgcn_s_setprio(1);
            #pragma unroll
            for (int rt = 0; rt < 4; ++rt)
                #pragma unroll
                for (int ct = 0; ct < 4; ++ct)
                    acc[rt][ct] = mfma16(ah[rt], bh[ct], acc[rt][ct]);
            __builtin_amdgcn_s_setprio(0);
            if (t < 7) *(s16x8*)(smem + nxt*8192 + awr) = an;
            __syncthreads();
        }
    }

    // Write WhT[bn][f][i] hi/lo. D: row = rt*16 + g*4 + r, col = f.
    const size_t wbT = (size_t)bn * FDIM * NODES;
    #pragma unroll
    for (int rt = 0; rt < 4; ++rt) {
        const int orow = i0 + rt * 16 + g * 4;
        #pragma unroll
        for (int ct = 0; ct < 4; ++ct) {
            const int f = w * 64 + ct * 16 + fb;
            s16x4 h4, l4;
            #pragma unroll
            for (int r = 0; r < 4; ++r) {
                float x = acc[rt][ct][r];
                unsigned short hh = f2bfu(x);
                h4[r] = (short)hh;
                l4[r] = (short)f2bfu(x - bfu2f(hh));
            }
            *(s16x4*)(WhTHi + wbT + (size_t)f * NODES + orow) = h4;
            *(s16x4*)(WhTLo + wbT + (size_t)f * NODES + orow) = l4;
        }
    }

    // src/dst reduction (fp32 accumulator path).
    float a1v[4], a2v[4];
    #pragma unroll
    for (int ct = 0; ct < 4; ++ct) {
        const int f = w * 64 + ct * 16 + fb;
        if (flag) {
            a1v[ct] = ((const float*)av)[f];
            a2v[ct] = ((const float*)av)[FDIM + f];
        } else {
            a1v[ct] = bfu2f(((const unsigned short*)av)[f]);
            a2v[ct] = bfu2f(((const unsigned short*)av)[FDIM + f]);
        }
    }
    float* red1 = (float*)smem;          // aliases dead A bufs
    float* red2 = red1 + 256;
    #pragma unroll
    for (int rt = 0; rt < 4; ++rt) {
        #pragma unroll
        for (int r = 0; r < 4; ++r) {
            float s1 = 0.f, s2 = 0.f;
            #pragma unroll
            for (int ct = 0; ct < 4; ++ct) {
                s1 = fmaf(acc[rt][ct][r], a1v[ct], s1);
                s2 = fmaf(acc[rt][ct][r], a2v[ct], s2);
            }
            #pragma unroll
            for (int off = 1; off <= 8; off <<= 1) {
                s1 += __shfl_xor(s1, off);
                s2 += __shfl_xor(s2, off);
            }
            if (fb == 0) {
                red1[w * 64 + rt * 16 + g * 4 + r] = s1;
                red2[w * 64 + rt * 16 + g * 4 + r] = s2;
            }
        }
    }
    __syncthreads();
    if (tid < 64) {
        srcv[bn * NODES + i0 + tid] =
            red1[tid] + red1[64 + tid] + red1[128 + tid] + red1[192 + tid];
        dstv[bn * NODES + i0 + tid] =
            red2[tid] + red2[64 + tid] + red2[128 + tid] + red2[192 + tid];
    }
}

// ---------------- KB: fused softmax + att@Wh + elu ----------------
// 512 blocks (XCD-swizzled) x 512 thr (8 waves). 64 rows, 256 cols, K=512.
// Wave w owns cols [w*32, w*32+32): B staging wave-private -> barrier-free
// K-loop, TRUE 2-tile lookahead (stage first, then vmcnt(8)).
__global__ __launch_bounds__(512, 2) void pv_gemm(
    const short* __restrict__ WhTHi, const short* __restrict__ WhTLo,
    const float* __restrict__ srcv, const float* __restrict__ dstv,
    const int* __restrict__ adj, const int* __restrict__ flagp,
    void* __restrict__ out)
{
    __shared__ __align__(16) char smem[163840];   // Ps 64K | 3 x (hi16K+lo16K)

    const int flag = *flagp;
    const int b0 = blockIdx.x;
    const int blk = (b0 & 7) * 64 + (b0 >> 3);   // bijective: 512 % 8 == 0
    const int bn  = blk >> 3;
    const int i0  = (blk & 7) * 64;
    const int tid = threadIdx.x;
    const int w = tid >> 6, l = tid & 63;

    const short* bhig = WhTHi + (size_t)bn * FDIM * NODES;
    const short* blog = WhTLo + (size_t)bn * FDIM * NODES;

    // wave-private B staging: wave w stages its own f-slice [w*32, w*32+32).
    const int sf0 = w * 32 + (l >> 2);
    const int sf1 = sf0 + 16;
    const int sl  = l & 3;
    const short* gH0 = bhig + (size_t)sf0 * NODES + (sl ^ SWZ(sf0)) * 8;
    const short* gH1 = bhig + (size_t)sf1 * NODES + (sl ^ SWZ(sf1)) * 8;
    const short* gL0 = blog + (size_t)sf0 * NODES + (sl ^ SWZ(sf0)) * 8;
    const short* gL1 = blog + (size_t)sf1 * NODES + (sl ^ SWZ(sf1)) * 8;
    const int dB = (w * 32) * 64 + l * 16;   // hi dest (call 0) within buf

    auto stage = [&](int buf, int t) {
        const int ko = t * 32;
        char* base = smem + 65536 + buf * 32768;
        gll16(gH0 + ko, base + dB);
        gll16(gH1 + ko, base + dB + 1024);
        gll16(gL0 + ko, base + 16384 + dB);
        gll16(gL1 + ko, base + 16384 + dB + 1024);
    };

    stage(0, 0);
    stage(1, 1);   // tiles 0,1 land while softmax runs

    // ---- softmax: wave w -> rows w*8..w*8+8; lane l covers j = 8l..8l+8 ----
    {
        const float* drow = dstv + bn * NODES;
        const int j = l * 8;
        for (int rr = 0; rr < 8; ++rr) {
            const int r = w * 8 + rr;
            const int* adjrow = adj + (size_t)(i0 + r) * NODES;
            const float srow = srcv[bn * NODES + i0 + r];
            const i32x4 q0 = *(const i32x4*)(adjrow + j);
            const i32x4 q1 = *(const i32x4*)(adjrow + j + 4);
            const f32x4 d0 = *(const f32x4*)(drow + j);
            const f32x4 d1 = *(const f32x4*)(drow + j + 4);
            float e[8];
            #pragma unroll
            for (int k = 0; k < 4; ++k) {
                float ev = srow + d0[k];
                ev = (ev > 0.f) ? ev : ALPHA * ev;
                e[k] = (q0[k] > 0) ? ev : MASK_VAL;
                float ew = srow + d1[k];
                ew = (ew > 0.f) ? ew : ALPHA * ew;
                e[4 + k] = (q1[k] > 0) ? ew : MASK_VAL;
            }
            float m = e[0];
            #pragma unroll
            for (int k = 1; k < 8; ++k) m = fmaxf(m, e[k]);
            #pragma unroll
            for (int off = 1; off <= 32; off <<= 1) m = fmaxf(m, __shfl_xor(m, off));
            float p[8], s = 0.f;
            #pragma unroll
            for (int k = 0; k < 8; ++k) {
                p[k] = __expf(e[k] - m);   // masked -> 0; all-masked row -> 1
                s += p[k];
            }
            #pragma unroll
            for (int off = 1; off <= 32; off <<= 1) s += __shfl_xor(s, off);
            const float isum = 1.0f / s;
            s16x8 ph;
            #pragma unroll
            for (int k = 0; k < 8; ++k) ph[k] = (short)f2bfu(p[k] * isum);
            // chunk l stored at slot l ^ (r&7)
            *(s16x8*)(smem + r * 1024 + ((l ^ (r & 7)) * 16)) = ph;
        }
    }
    // Ps visible to all waves; keep prologue B loads in flight (lgkm-only drain)
    asm volatile("s_waitcnt lgkmcnt(0)" ::: "memory");
    __builtin_amdgcn_s_barrier();

    // ---- PV GEMM: 16 K-steps, barrier-free, 2-tile-lookahead pipeline ----
    const int fb = l & 15, g = l >> 4;

    unsigned boff[2];
    #pragma unroll
    for (int ct = 0; ct < 2; ++ct) {
        const int f = w * 32 + ct * 16 + fb;
        boff[ct] = (unsigned)(65536 + f * 64 + (g ^ SWZ(f)) * 16);
    }

    f32x4 acc[4][2];
    #pragma unroll
    for (int rt = 0; rt < 4; ++rt)
        #pragma unroll
        for (int ct = 0; ct < 2; ++ct) acc[rt][ct] = f32x4{0.f,0.f,0.f,0.f};

    int cur = 0;
    for (int t = 0; t < 16; ++t) {
        // issue next-next tile FIRST (into LRU buf, consumed at t-1), ...
        if (t < 14) {
            int nb = cur + 2; if (nb >= 3) nb -= 3;
            stage(nb, t + 2);
        }
        // ... THEN wait with a count that keeps 2 tiles (8 loads) in flight.
        if (t < 14)       asm volatile("s_waitcnt vmcnt(8)" ::: "memory");
        else if (t == 14) asm volatile("s_waitcnt vmcnt(4)" ::: "memory");
        else              asm volatile("s_waitcnt vmcnt(0)" ::: "memory");

        const unsigned bbase = (unsigned)(cur * 32768);
        s16x8 bh[2], bl[2];
        #pragma unroll
        for (int ct = 0; ct < 2; ++ct) {
            bh[ct] = *(const s16x8*)(smem + bbase + boff[ct]);
            bl[ct] = *(const s16x8*)(smem + bbase + boff[ct] + 16384);
        }
        s16x8 af[4];
        #pragma unroll
        for (int rt = 0; rt < 4; ++rt) {
            const int row = rt * 16 + fb;
            const unsigned seg = (unsigned)(t * 4 + g) ^ (unsigned)(row & 7);
            af[rt] = *(const s16x8*)(smem + (unsigned)(row * 1024) + seg * 16);
        }
        __builtin_amdgcn_s_setprio(1);
        #pragma unroll
        for (int rt = 0; rt < 4; ++rt) {
            acc[rt][0] = mfma16(af[rt], bh[0], acc[rt][0]);
            acc[rt][0] = mfma16(af[rt], bl[0], acc[rt][0]);
            acc[rt][1] = mfma16(af[rt], bh[1], acc[rt][1]);
            acc[rt][1] = mfma16(af[rt], bl[1], acc[rt][1]);
        }
        __builtin_amdgcn_s_setprio(0);
        cur = cur + 1; if (cur == 3) cur = 0;
    }

    // epilogue: elu, store (P pre-normalized). D row = rt*16 + g*4 + r.
    #pragma unroll
    for (int rt = 0; rt < 4; ++rt) {
        #pragma unroll
        for (int ct = 0; ct < 2; ++ct) {
            const int f = w * 32 + ct * 16 + fb;
            #pragma unroll
            for (int r = 0; r < 4; ++r) {
                float v = acc[rt][ct][r];
                v = (v > 0.f) ? v : expm1f(v);
                const size_t o = ((size_t)bn * NODES + i0 + rt * 16 + g * 4 + r) * FDIM + f;
                if (flag) ((float*)out)[o] = v;
                else      ((unsigned short*)out)[o] = f2bfu(v);
            }
        }
    }
}

extern "C" void kernel_launch(void* const* d_in, const int* in_sizes, int n_in,
                              void* d_out, int out_size, void* d_ws, size_t ws_size,
                              hipStream_t stream)
{
    const void* h   = d_in[0];
    const int*  adj = (const int*)d_in[1];
    const void* W   = d_in[2];
    const void* a   = d_in[3];

    // ws layout: flag 256B | src 128K | dst 128K | WtHi 128K | WtLo 128K
    //            | WhTHi 16.78M | WhTLo 16.78M   (~34.1 MB total)
    int*   flag  = (int*)d_ws;
    float* srcv  = (float*)d_ws + 64;
    float* dstv  = srcv + BN * NODES;
    short* WtHi  = (short*)(dstv + BN * NODES);
    short* WtLo  = WtHi + FDIM * FDIM;
    short* WhTHi = WtLo + FDIM * FDIM;
    short* WhTLo = WhTHi + (size_t)BN * FDIM * NODES;

    detect_kernel<<<1, 256, 0, stream>>>((const unsigned short*)h, flag);
    prep_w_kernel<<<dim3(16, 16), 256, 0, stream>>>(W, flag, WtHi, WtLo);
    wh_gemm<<<512, 256, 0, stream>>>(h, WtHi, WtLo, a, flag,
                                     WhTHi, WhTLo, srcv, dstv);
    pv_gemm<<<512, 512, 0, stream>>>(WhTHi, WhTLo, srcv, dstv, adj, flag, d_out);
}